// Round 1
// baseline (7470.518 us; speedup 1.0000x reference)
//
#include <hip/hip_runtime.h>
#include <stdint.h>

typedef unsigned short ushort_t;
typedef __attribute__((ext_vector_type(8))) short short8;
typedef __attribute__((ext_vector_type(4))) float float4v;
typedef __attribute__((ext_vector_type(4))) int int4v;

#define TSTEPS 512
#define NBATCH 128
#define HID 256
#define NIN 64
#define RB 32           // ring depth (steps)

// workspace layout (bytes)
#define OFF_FLAGS   0u
#define OFF_BIAS    4096u
#define OFF_H1R     16384u
#define RING_BYTES  (RB*2u*NBATCH*HID*2u)          // 4,194,304
#define OFF_H2R     (OFF_H1R + RING_BYTES)
#define OFF_WF1     (OFF_H2R + RING_BYTES)
#define WF1_FRAGS   (16*8*4*4)                     // 2048 fragments of 1KB
#define OFF_WF2     (OFF_WF1 + WF1_FRAGS*1024u)
#define WF2_FRAGS   (16*8*6*4)                     // 3072 fragments of 1KB

__device__ __forceinline__ ushort_t bf16h(float f) {
    unsigned u = __float_as_uint(f);
    u += 0x7fffu + ((u >> 16) & 1u);
    return (ushort_t)(u >> 16);
}
__device__ __forceinline__ float bf16f(ushort_t h) {
    return __uint_as_float(((unsigned)h) << 16);
}

// ---------------- prep kernels ----------------

__global__ void prep_misc(const float* bxh1, const float* bhh1,
                          const float* bxh2, const float* bhh2,
                          float* bias, int* flags, ushort_t* h1r, ushort_t* h2r)
{
    int n = blockIdx.x * blockDim.x + threadIdx.x;
    if (n < 1024)       bias[n] = bxh1[n] + bhh1[n];
    else if (n < 2048)  bias[n] = bxh2[n - 1024] + bhh2[n - 1024];
    else if (n < 2304)  flags[n - 2048] = 0;
    else if (n < 2304 + 65536)  h1r[(RB-1)*2*NBATCH*HID + (n - 2304)] = 0;
    else if (n < 2304 + 131072) h2r[(RB-1)*2*NBATCH*HID + (n - 2304 - 65536)] = 0;
}

// Build MFMA B-fragments (hi/lo split weights) in exact consumption order:
// fragment id = ((slice*8 + wave)*F + i)*4 + ntile ; each fragment = [lane][8] bf16.
// B[k][n] = W[gate_row(n)][k], lane&15 = n, k = (lane>>4)*8 + j.
__global__ void prep_wf(const float* Wxh1, const float* Whh1,
                        const float* Wxh2, const float* Whh2,
                        ushort_t* wf1, ushort_t* wf2)
{
    int n = blockIdx.x * blockDim.x + threadIdx.x;
    const int L1E = WF1_FRAGS * 512;
    const int L2E = WF2_FRAGS * 512;
    if (n >= L1E + L2E) return;
    int layer = (n >= L1E) ? 1 : 0;
    int e = layer ? (n - L1E) : n;
    int el = e & 511;
    int f  = e >> 9;
    int lane = el >> 3, j = el & 7;
    int nt = f & 3;
    int rem = f >> 2;
    int i, wv, slice, F, S;
    if (!layer) { F = 4; S = 10; i = rem & 3; wv = (rem >> 2) & 7; slice = rem >> 5; }
    else        { F = 6; S = 16; i = rem % 6; int r2 = rem / 6; wv = r2 & 7; slice = r2 >> 3; }
    int fg = wv * F + i;
    int col = lane & 15;
    int row = nt * 256 + slice * 16 + col;
    float val = 0.f;
    if (fg < 3 * S) {
        int sec = (fg < S) ? 0 : ((fg < 2 * S) ? 1 : 2);
        int ks = (fg - sec * S) * 32 + (lane >> 4) * 8 + j;
        float w;
        if (!layer) w = (ks < 256) ? Whh1[row * 256 + ks] : Wxh1[row * 64 + (ks - 256)];
        else        w = (ks < 256) ? Wxh2[row * 256 + ks] : Whh2[row * 256 + (ks - 256)];
        ushort_t hi = bf16h(w);
        val = (sec < 2) ? bf16f(hi) : (w - bf16f(hi));
    }
    (layer ? wf2 : wf1)[e] = bf16h(val);
}

// ---------------- recurrent kernel ----------------
// grid = 256 WGs x 512 threads. blockIdx%8 = batch group (XCD swizzle),
// blockIdx/8 in [0,16) -> layer1 slice, [16,32) -> layer2 slice.
// Each WG owns 16 h-indices (4 MFMA N-tiles: i,f,z,o) for 16 batch rows.
// K x {hi*hi, lo*hi, hi*lo} products split across the 8 waves; LDS tree-reduce;
// wave0 does the sLSTM cell update and publishes h (hi/lo bf16) + release flag.

template<int LAYER, int F, int S, int PITCH, int NOCT>
__device__ __forceinline__ void run_layer(
    int g, int slice, int tid, const float* __restrict__ x,
    int* flags, const float* bias,
    ushort_t* h1r, ushort_t* h2r, const ushort_t* wfrag,
    ushort_t* sA, ushort_t* sB, float (*red)[64][16])
{
    const int wv = tid >> 6, lane = tid & 63;
    const int mrow = lane & 15, q = lane >> 4;
    int* f1 = flags + g * 16;
    int* f2 = flags + 128 + g * 16;
    int* myflag = flags + LAYER * 128 + g * 16 + slice;

    // persistent B fragments in VGPRs
    short8 bw[4][F];
    {
        const ushort_t* base = wfrag + (size_t)((slice * 8 + wv) * F) * 4 * 512;
        #pragma unroll
        for (int i = 0; i < F; i++)
            #pragma unroll
            for (int nt = 0; nt < 4; nt++)
                bw[nt][i] = *(const short8*)(base + (i * 4 + nt) * 512 + lane * 8);
    }

    float bs[4];
    #pragma unroll
    for (int nt = 0; nt < 4; nt++)
        bs[nt] = bias[LAYER * 1024 + nt * 256 + slice * 16 + mrow];

    float cst[4] = {0,0,0,0}, mst[4] = {0,0,0,0}, nst[4] = {0,0,0,0};

    for (int t = 0; t < TSTEPS; t++) {
        // ---- waits (wave0 lanes spin on flags) ----
        if (tid < 64) {
            int* p = nullptr; int thr = 0;
            if (LAYER == 0) {
                if (lane < 16)      { p = f1 + lane;        thr = t; }      // peers: h1[t-1]
                else if (lane < 32) { p = f2 + (lane - 16); thr = t - 30; } // ring backpressure
            } else {
                if (lane < 16)      { p = f1 + lane;        thr = t + 1; }  // h1[t]
                else if (lane < 32) { p = f2 + (lane - 16); thr = t; }      // peers: h2[t-1]
            }
            if (p)
                while (__hip_atomic_load(p, __ATOMIC_ACQUIRE, __HIP_MEMORY_SCOPE_AGENT) < thr) { }
        }
        __syncthreads();

        // ---- stage K-vectors into LDS (hi -> sA, lo -> sB) ----
        {
            int slot1 = (LAYER == 0) ? ((t - 1) & (RB - 1)) : (t & (RB - 1));
            int slot2 = (t - 1) & (RB - 1);
            for (int u = tid; u < 16 * NOCT * 2; u += 512) {
                int v = (u >= 16 * NOCT) ? 1 : 0;
                int uu = u - v * 16 * NOCT;
                int r = uu / NOCT, c8 = uu % NOCT;
                int row = g * 16 + r;
                ushort_t* dst = (v ? sB : sA) + r * PITCH + c8 * 8;
                if (c8 < 32) {
                    const ushort_t* src = h1r + ((size_t)(slot1 * 2 + v) * NBATCH + row) * HID + c8 * 8;
                    *(int4v*)dst = *(const int4v*)src;
                } else if (LAYER == 0) {
                    // split x on the fly
                    const float* xsrc = x + ((size_t)row * TSTEPS + t) * NIN + (c8 - 32) * 8;
                    union { ushort_t u8[8]; int4v v4; } pk;
                    #pragma unroll
                    for (int z = 0; z < 8; z++) {
                        float xv = xsrc[z];
                        ushort_t hi = bf16h(xv);
                        pk.u8[z] = v ? bf16h(xv - bf16f(hi)) : hi;
                    }
                    *(int4v*)dst = pk.v4;
                } else {
                    const ushort_t* src = h2r + ((size_t)(slot2 * 2 + v) * NBATCH + row) * HID + (c8 - 32) * 8;
                    *(int4v*)dst = *(const int4v*)src;
                }
            }
        }
        __syncthreads();

        // ---- MFMA: this wave's K-chunks across the 4 gate N-tiles ----
        float4v acc[4] = {};
        #pragma unroll
        for (int i = 0; i < F; i++) {
            const int fg = wv * F + i;
            short8 a;
            if (fg < 3 * S) {
                int sec = (fg >= S && fg < 2 * S) ? 1 : 0;
                int ks = ((fg < S) ? fg : ((fg < 2 * S) ? fg - S : fg - 2 * S)) * 32;
                const ushort_t* ap = (sec ? sB : sA) + mrow * PITCH + ks + q * 8;
                a = *(const short8*)ap;
            } else {
                a = (short8){0,0,0,0,0,0,0,0};
            }
            #pragma unroll
            for (int nt = 0; nt < 4; nt++)
                acc[nt] = __builtin_amdgcn_mfma_f32_16x16x32_bf16(a, bw[nt][i], acc[nt], 0, 0, 0);
        }

        // ---- cross-wave tree reduction in LDS ----
        if (wv >= 4) {
            #pragma unroll
            for (int nt = 0; nt < 4; nt++) *(float4v*)&red[wv][lane][nt * 4] = acc[nt];
        }
        __syncthreads();
        if (wv < 4) {
            #pragma unroll
            for (int nt = 0; nt < 4; nt++) acc[nt] += *(const float4v*)&red[wv + 4][lane][nt * 4];
            if (wv >= 2) {
                #pragma unroll
                for (int nt = 0; nt < 4; nt++) *(float4v*)&red[wv][lane][nt * 4] = acc[nt];
            }
        }
        __syncthreads();
        if (wv < 2) {
            #pragma unroll
            for (int nt = 0; nt < 4; nt++) acc[nt] += *(const float4v*)&red[wv + 2][lane][nt * 4];
            if (wv == 1) {
                #pragma unroll
                for (int nt = 0; nt < 4; nt++) *(float4v*)&red[1][lane][nt * 4] = acc[nt];
            }
        }
        __syncthreads();

        // ---- wave0: cell update + publish ----
        if (wv == 0) {
            #pragma unroll
            for (int nt = 0; nt < 4; nt++) acc[nt] += *(const float4v*)&red[1][lane][nt * 4];

            ushort_t* ring = LAYER ? h2r : h1r;
            int slotW = t & (RB - 1);
            #pragma unroll
            for (int r = 0; r < 4; r++) {
                float ig  = acc[0][r] + bs[0];
                float fgt = acc[1][r] + bs[1];
                float zg  = acc[2][r] + bs[2];
                float og  = acc[3][r] + bs[3];
                float zc = fminf(fmaxf(zg, -15.f), 15.f);
                float e2 = __expf(2.f * zc);
                float zt = (e2 - 1.f) / (e2 + 1.f);
                float ot = 1.f / (1.f + __expf(-og));
                float mt = fmaxf(fgt + mst[r], ig);
                float it = __expf(ig - mt);
                float ft = __expf(fgt + mst[r] - mt);
                cst[r] = ft * cst[r] + it * zt;
                nst[r] = ft * nst[r] + it;
                mst[r] = mt;
                float h = ot * (cst[r] / nst[r]);
                ushort_t hi = bf16h(h);
                ushort_t lo = bf16h(h - bf16f(hi));
                int row = g * 16 + q * 4 + r;
                int col = slice * 16 + mrow;
                ring[((size_t)(slotW * 2 + 0) * NBATCH + row) * HID + col] = hi;
                ring[((size_t)(slotW * 2 + 1) * NBATCH + row) * HID + col] = lo;
            }
            __threadfence();
            if (lane == 0)
                __hip_atomic_store(myflag, t + 1, __ATOMIC_RELEASE, __HIP_MEMORY_SCOPE_AGENT);
        }
    }
}

__global__ __launch_bounds__(512, 2) void recur(
    const float* __restrict__ x,
    int* flags, const float* bias,
    ushort_t* h1r, ushort_t* h2r, const ushort_t* wf1, const ushort_t* wf2)
{
    __shared__ ushort_t sA[16 * 520];
    __shared__ ushort_t sB[16 * 520];
    __shared__ float red[8][64][16];
    int g = blockIdx.x & 7;
    int loc = blockIdx.x >> 3;
    if (loc < 16)
        run_layer<0, 4, 10, 328, 40>(g, loc, threadIdx.x, x, flags, bias, h1r, h2r, wf1, sA, sB, red);
    else
        run_layer<1, 6, 16, 520, 64>(g, loc - 16, threadIdx.x, x, flags, bias, h1r, h2r, wf2, sA, sB, red);
}

// ---------------- head MLP ----------------

__global__ void head_mlp(const ushort_t* h2r, const float* W1, const float* b1,
                         const float* W2, const float* b2, const float* W3, const float* b3,
                         float* out)
{
    __shared__ float h[256];
    __shared__ float a1[128];
    __shared__ float a2[64];
    int b = blockIdx.x, j = threadIdx.x;
    const int slot = (TSTEPS - 1) & (RB - 1);
    for (int k = j; k < 256; k += 128)
        h[k] = bf16f(h2r[((size_t)(slot * 2 + 0) * NBATCH + b) * HID + k]) +
               bf16f(h2r[((size_t)(slot * 2 + 1) * NBATCH + b) * HID + k]);
    __syncthreads();
    float s = b1[j];
    for (int k = 0; k < 256; k++) s += W1[j * 256 + k] * h[k];
    a1[j] = fmaxf(s, 0.f);
    __syncthreads();
    if (j < 64) {
        float s2 = b2[j];
        for (int k = 0; k < 128; k++) s2 += W2[j * 128 + k] * a1[k];
        a2[j] = fmaxf(s2, 0.f);
    }
    __syncthreads();
    if (j == 0) {
        float s3 = b3[0];
        for (int k = 0; k < 64; k++) s3 += W3[k] * a2[k];
        out[b] = s3;
    }
}

// ---------------- launch ----------------

extern "C" void kernel_launch(void* const* d_in, const int* in_sizes, int n_in,
                              void* d_out, int out_size, void* d_ws, size_t ws_size,
                              hipStream_t stream)
{
    const float* x    = (const float*)d_in[0];
    const float* Wxh1 = (const float*)d_in[1];
    const float* bxh1 = (const float*)d_in[2];
    const float* Whh1 = (const float*)d_in[3];
    const float* bhh1 = (const float*)d_in[4];
    const float* Wxh2 = (const float*)d_in[5];
    const float* bxh2 = (const float*)d_in[6];
    const float* Whh2 = (const float*)d_in[7];
    const float* bhh2 = (const float*)d_in[8];
    const float* W1   = (const float*)d_in[9];
    const float* b1   = (const float*)d_in[10];
    const float* W2   = (const float*)d_in[11];
    const float* b2   = (const float*)d_in[12];
    const float* W3   = (const float*)d_in[13];
    const float* b3   = (const float*)d_in[14];

    char* w = (char*)d_ws;
    int*      flags = (int*)(w + OFF_FLAGS);
    float*    bias  = (float*)(w + OFF_BIAS);
    ushort_t* h1r   = (ushort_t*)(w + OFF_H1R);
    ushort_t* h2r   = (ushort_t*)(w + OFF_H2R);
    ushort_t* wf1   = (ushort_t*)(w + OFF_WF1);
    ushort_t* wf2   = (ushort_t*)(w + OFF_WF2);

    prep_misc<<<(2304 + 131072 + 255) / 256, 256, 0, stream>>>(bxh1, bhh1, bxh2, bhh2,
                                                               bias, flags, h1r, h2r);
    prep_wf<<<((WF1_FRAGS + WF2_FRAGS) * 512 + 255) / 256, 256, 0, stream>>>(
        Wxh1, Whh1, Wxh2, Whh2, wf1, wf2);

    const float* xp = x;
    void* args[] = { (void*)&xp, (void*)&flags, (void*)&bias,
                     (void*)&h1r, (void*)&h2r, (void*)&wf1, (void*)&wf2 };
    hipLaunchCooperativeKernel((void*)recur, dim3(256), dim3(512), args, 0, stream);

    head_mlp<<<NBATCH, 128, 0, stream>>>(h2r, W1, b1, W2, b2, W3, b3, (float*)d_out);
}

// Round 2
// 1937.176 us; speedup vs baseline: 3.8564x; 3.8564x over previous
//
#include <hip/hip_runtime.h>
#include <stdint.h>

typedef unsigned short ushort_t;
typedef __attribute__((ext_vector_type(8))) short short8;
typedef __attribute__((ext_vector_type(4))) float float4v;
typedef __attribute__((ext_vector_type(4))) int int4v;

#define TSTEPS 512
#define NBATCH 128
#define HID 256
#define NIN 64
#define RB 32           // ring depth (steps)
#define NBHID (NBATCH*HID)

// workspace layout (bytes)
#define OFF_FLAGS   0u
#define OFF_BIAS    4096u
#define OFF_H1R     16384u
#define RING_BYTES  (RB*2u*NBATCH*HID*2u)          // 4,194,304
#define OFF_H2R     (OFF_H1R + RING_BYTES)
#define OFF_WF1     (OFF_H2R + RING_BYTES)
#define WF1_FRAGS   (16*8*4*4)                     // 2048 fragments of 1KB
#define OFF_WF2     (OFF_WF1 + WF1_FRAGS*1024u)
#define WF2_FRAGS   (16*8*6*4)                     // 3072 fragments of 1KB
#define OFF_HOUT    (OFF_WF2 + WF2_FRAGS*1024u)    // 128*256 fp32 = 128KB

__device__ __forceinline__ ushort_t bf16h(float f) {
    unsigned u = __float_as_uint(f);
    u += 0x7fffu + ((u >> 16) & 1u);
    return (ushort_t)(u >> 16);
}
__device__ __forceinline__ float bf16f(ushort_t h) {
    return __uint_as_float(((unsigned)h) << 16);
}

// ---- coherent (IC-level) access helpers: sc0 sc1 = bypass L1+L2, no cache maintenance ----

__device__ __forceinline__ int ld_cg_i32(const void* p) {
    int r;
    asm volatile("global_load_dword %0, %1, off sc0 sc1\n\ts_waitcnt vmcnt(0)"
                 : "=v"(r) : "v"(p) : "memory");
    return r;
}
__device__ __forceinline__ float ld_cg_f32(const void* p) {
    float r;
    asm volatile("global_load_dword %0, %1, off sc0 sc1\n\ts_waitcnt vmcnt(0)"
                 : "=v"(r) : "v"(p) : "memory");
    return r;
}
__device__ __forceinline__ void ld_cg_x2(int4v& a, int4v& b, const void* pa, const void* pb) {
    asm volatile("global_load_dwordx4 %0, %2, off sc0 sc1\n\t"
                 "global_load_dwordx4 %1, %3, off sc0 sc1\n\t"
                 "s_waitcnt vmcnt(0)"
                 : "=&v"(a), "=&v"(b)
                 : "v"(pa), "v"(pb) : "memory");
}
__device__ __forceinline__ void ld_cg_x4(int4v& a, int4v& b, int4v& c, int4v& d,
                                         const void* pa, const void* pb,
                                         const void* pc, const void* pd) {
    asm volatile("global_load_dwordx4 %0, %4, off sc0 sc1\n\t"
                 "global_load_dwordx4 %1, %5, off sc0 sc1\n\t"
                 "global_load_dwordx4 %2, %6, off sc0 sc1\n\t"
                 "global_load_dwordx4 %3, %7, off sc0 sc1\n\t"
                 "s_waitcnt vmcnt(0)"
                 : "=&v"(a), "=&v"(b), "=&v"(c), "=&v"(d)
                 : "v"(pa), "v"(pb), "v"(pc), "v"(pd) : "memory");
}
__device__ __forceinline__ void st_cg_u16(void* p, unsigned v) {
    asm volatile("global_store_short %0, %1, off sc0 sc1" :: "v"(p), "v"(v) : "memory");
}
__device__ __forceinline__ void st_cg_f32(void* p, float v) {
    asm volatile("global_store_dword %0, %1, off sc0 sc1" :: "v"(p), "v"(v) : "memory");
}
// release: drain all this wave's stores (they're write-through), then publish flag
__device__ __forceinline__ void flag_release(void* p, int v) {
    asm volatile("s_waitcnt vmcnt(0)\n\tglobal_store_dword %0, %1, off sc0 sc1"
                 :: "v"(p), "v"(v) : "memory");
}

// ---------------- prep kernels ----------------

__global__ void prep_misc(const float* bxh1, const float* bhh1,
                          const float* bxh2, const float* bhh2,
                          float* bias, int* flags, ushort_t* h1r, ushort_t* h2r)
{
    int n = blockIdx.x * blockDim.x + threadIdx.x;
    if (n < 1024)       bias[n] = bxh1[n] + bhh1[n];
    else if (n < 2048)  bias[n] = bxh2[n - 1024] + bhh2[n - 1024];
    else if (n < 2304)  flags[n - 2048] = 0;
    else if (n < 2304 + 65536)  h1r[(RB-1)*2*NBHID + (n - 2304)] = 0;
    else if (n < 2304 + 131072) h2r[(RB-1)*2*NBHID + (n - 2304 - 65536)] = 0;
}

// Build MFMA B-fragments (hi/lo split weights) in exact consumption order:
// fragment id = ((slice*8 + wave)*F + i)*4 + ntile ; each fragment = [lane][8] bf16.
__global__ void prep_wf(const float* Wxh1, const float* Whh1,
                        const float* Wxh2, const float* Whh2,
                        ushort_t* wf1, ushort_t* wf2)
{
    int n = blockIdx.x * blockDim.x + threadIdx.x;
    const int L1E = WF1_FRAGS * 512;
    const int L2E = WF2_FRAGS * 512;
    if (n >= L1E + L2E) return;
    int layer = (n >= L1E) ? 1 : 0;
    int e = layer ? (n - L1E) : n;
    int el = e & 511;
    int f  = e >> 9;
    int lane = el >> 3, j = el & 7;
    int nt = f & 3;
    int rem = f >> 2;
    int i, wv, slice, F, S;
    if (!layer) { F = 4; S = 10; i = rem & 3; wv = (rem >> 2) & 7; slice = rem >> 5; }
    else        { F = 6; S = 16; i = rem % 6; int r2 = rem / 6; wv = r2 & 7; slice = r2 >> 3; }
    int fg = wv * F + i;
    int col = lane & 15;
    int row = nt * 256 + slice * 16 + col;
    float val = 0.f;
    if (fg < 3 * S) {
        int sec = (fg < S) ? 0 : ((fg < 2 * S) ? 1 : 2);
        int ks = (fg - sec * S) * 32 + (lane >> 4) * 8 + j;
        float w;
        if (!layer) w = (ks < 256) ? Whh1[row * 256 + ks] : Wxh1[row * 64 + (ks - 256)];
        else        w = (ks < 256) ? Wxh2[row * 256 + ks] : Whh2[row * 256 + (ks - 256)];
        ushort_t hi = bf16h(w);
        val = (sec < 2) ? bf16f(hi) : (w - bf16f(hi));
    }
    (layer ? wf2 : wf1)[e] = bf16h(val);
}

// ---------------- recurrent kernel ----------------
// grid = 256 WGs x 512 threads. blockIdx%8 = batch group, blockIdx/8: [0,16) layer1
// slice, [16,32) layer2 slice. All cross-WG data through IC via sc0sc1 accesses.

template<int LAYER, int F, int S, int PITCH>
__device__ __forceinline__ void run_layer(
    int g, int slice, int tid, const float* __restrict__ x,
    int* flags, const float* bias,
    ushort_t* h1r, ushort_t* h2r, const ushort_t* wfrag, float* hOut,
    ushort_t* sA, ushort_t* sB, float (*red)[4][64][4])
{
    const int wv = tid >> 6, lane = tid & 63;
    const int mrow = lane & 15, q = lane >> 4;
    int* f1 = flags + g * 16;
    int* f2 = flags + 128 + g * 16;
    int* myflag = flags + LAYER * 128 + g * 16 + slice;

    // persistent B fragments in VGPRs
    short8 bw[4][F];
    {
        const ushort_t* base = wfrag + (size_t)((slice * 8 + wv) * F) * 4 * 512;
        #pragma unroll
        for (int i = 0; i < F; i++)
            #pragma unroll
            for (int nt = 0; nt < 4; nt++)
                bw[nt][i] = *(const short8*)(base + (i * 4 + nt) * 512 + lane * 8);
    }

    float bs[4];
    #pragma unroll
    for (int nt = 0; nt < 4; nt++)
        bs[nt] = bias[LAYER * 1024 + nt * 256 + slice * 16 + mrow];

    float cst[4] = {0,0,0,0}, mst[4] = {0,0,0,0}, nst[4] = {0,0,0,0};

    for (int t = 0; t < TSTEPS; t++) {
        // ---- x staging (layer1, waves 2-3; independent of flags) ----
        if (LAYER == 0 && tid >= 128 && tid < 256) {
            int idx = tid - 128;          // 0..127
            int r = idx >> 3, o = idx & 7;
            const float* xsrc = x + ((size_t)(g * 16 + r) * TSTEPS + t) * NIN + o * 8;
            float4v x0 = *(const float4v*)xsrc;
            float4v x1 = *(const float4v*)(xsrc + 4);
            float xs[8] = {x0[0], x0[1], x0[2], x0[3], x1[0], x1[1], x1[2], x1[3]};
            union { ushort_t u[8]; int4v v4; } hiP, loP;
            #pragma unroll
            for (int z = 0; z < 8; z++) {
                ushort_t hi = bf16h(xs[z]);
                hiP.u[z] = hi;
                loP.u[z] = bf16h(xs[z] - bf16f(hi));
            }
            *(int4v*)(sA + r * PITCH + (32 + o) * 8) = hiP.v4;
            *(int4v*)(sB + r * PITCH + (32 + o) * 8) = loP.v4;
        }

        // ---- flag waits (wave0, relaxed sc0sc1 polls — NO cache maintenance) ----
        if (tid < 64) {
            int* p = nullptr; int thr = 0;
            if (LAYER == 0) {
                if (lane < 16)      { p = f1 + lane;        thr = t; }      // peers: h1[t-1]
                else if (lane < 32) { p = f2 + (lane - 16); thr = t - 30; } // ring backpressure
            } else {
                if (lane < 16)      { p = f1 + lane;        thr = t + 1; }  // h1[t]
                else if (lane < 32) { p = f2 + (lane - 16); thr = t; }      // peers: h2[t-1]
            }
            if (p)
                while (ld_cg_i32(p) < thr) { }
        }
        __syncthreads();

        // ---- stage h K-vectors into LDS via IC (hi -> sA, lo -> sB) ----
        {
            int r = tid >> 5, k = tid & 31;
            int row = g * 16 + r;
            if (LAYER == 0) {
                int slot = (t - 1) & (RB - 1);
                const ushort_t* base = h1r + (size_t)slot * 2 * NBHID + (size_t)row * HID;
                const void* p0 = base + k * 8;                  // hi plane
                const void* p1 = base + (size_t)NBHID + k * 8;  // lo plane
                int4v d0, d1;
                ld_cg_x2(d0, d1, p0, p1);
                *(int4v*)(sA + r * PITCH + k * 8) = d0;
                *(int4v*)(sB + r * PITCH + k * 8) = d1;
            } else {
                int s1 = t & (RB - 1), s2 = (t - 1) & (RB - 1);
                const ushort_t* b1h = h1r + (size_t)s1 * 2 * NBHID + (size_t)row * HID;
                const ushort_t* b2h = h2r + (size_t)s2 * 2 * NBHID + (size_t)row * HID;
                const void* p0 = b1h + k * 8;                   // h1 hi
                const void* p1 = b2h + k * 8;                   // h2 hi
                const void* p2 = b1h + (size_t)NBHID + k * 8;   // h1 lo
                const void* p3 = b2h + (size_t)NBHID + k * 8;   // h2 lo
                int4v d0, d1, d2, d3;
                ld_cg_x4(d0, d1, d2, d3, p0, p1, p2, p3);
                *(int4v*)(sA + r * PITCH + k * 8)        = d0;
                *(int4v*)(sA + r * PITCH + (32 + k) * 8) = d1;
                *(int4v*)(sB + r * PITCH + k * 8)        = d2;
                *(int4v*)(sB + r * PITCH + (32 + k) * 8) = d3;
            }
        }
        __syncthreads();

        // ---- MFMA: this wave's K-chunks across the 4 gate N-tiles ----
        float4v acc[4] = {};
        #pragma unroll
        for (int i = 0; i < F; i++) {
            const int fg = wv * F + i;
            short8 a;
            if (fg < 3 * S) {
                int sec = (fg >= S && fg < 2 * S) ? 1 : 0;
                int ks = ((fg < S) ? fg : ((fg < 2 * S) ? fg - S : fg - 2 * S)) * 32;
                const ushort_t* ap = (sec ? sB : sA) + mrow * PITCH + ks + q * 8;
                a = *(const short8*)ap;
            } else {
                a = (short8){0,0,0,0,0,0,0,0};
            }
            #pragma unroll
            for (int nt = 0; nt < 4; nt++)
                acc[nt] = __builtin_amdgcn_mfma_f32_16x16x32_bf16(a, bw[nt][i], acc[nt], 0, 0, 0);
        }

        // ---- cross-wave tree reduction (lane-major layout: conflict-free) ----
        if (wv >= 4) {
            #pragma unroll
            for (int nt = 0; nt < 4; nt++) *(float4v*)red[wv][nt][lane] = acc[nt];
        }
        __syncthreads();
        if (wv < 4) {
            #pragma unroll
            for (int nt = 0; nt < 4; nt++) acc[nt] += *(const float4v*)red[wv + 4][nt][lane];
            if (wv >= 2) {
                #pragma unroll
                for (int nt = 0; nt < 4; nt++) *(float4v*)red[wv][nt][lane] = acc[nt];
            }
        }
        __syncthreads();
        if (wv < 2) {
            #pragma unroll
            for (int nt = 0; nt < 4; nt++) acc[nt] += *(const float4v*)red[wv + 2][nt][lane];
            if (wv == 1) {
                #pragma unroll
                for (int nt = 0; nt < 4; nt++) *(float4v*)red[1][nt][lane] = acc[nt];
            }
        }
        __syncthreads();

        // ---- wave0: cell update + publish (write-through, then release flag) ----
        if (wv == 0) {
            #pragma unroll
            for (int nt = 0; nt < 4; nt++) acc[nt] += *(const float4v*)red[1][nt][lane];

            ushort_t* ring = LAYER ? h2r : h1r;
            int slotW = t & (RB - 1);
            #pragma unroll
            for (int r = 0; r < 4; r++) {
                float ig  = acc[0][r] + bs[0];
                float fgt = acc[1][r] + bs[1];
                float zg  = acc[2][r] + bs[2];
                float og  = acc[3][r] + bs[3];
                float zc = fminf(fmaxf(zg, -15.f), 15.f);
                float e2 = __expf(2.f * zc);
                float zt = (e2 - 1.f) / (e2 + 1.f);
                float ot = 1.f / (1.f + __expf(-og));
                float mt = fmaxf(fgt + mst[r], ig);
                float it = __expf(ig - mt);
                float ft = __expf(fgt + mst[r] - mt);
                cst[r] = ft * cst[r] + it * zt;
                nst[r] = ft * nst[r] + it;
                mst[r] = mt;
                float h = ot * (cst[r] / nst[r]);
                ushort_t hi = bf16h(h);
                ushort_t lo = bf16h(h - bf16f(hi));
                int row = g * 16 + q * 4 + r;
                int col = slice * 16 + mrow;
                st_cg_u16(ring + ((size_t)(slotW * 2 + 0) * NBATCH + row) * HID + col, (unsigned)hi);
                st_cg_u16(ring + ((size_t)(slotW * 2 + 1) * NBATCH + row) * HID + col, (unsigned)lo);
                if (LAYER == 1 && t == TSTEPS - 1)
                    st_cg_f32(hOut + (size_t)row * HID + col, h);
            }
            if (lane == 0)
                flag_release(myflag, t + 1);
        }
    }
}

__global__ __launch_bounds__(512, 2) void recur(
    const float* __restrict__ x,
    int* flags, const float* bias,
    ushort_t* h1r, ushort_t* h2r, const ushort_t* wf1, const ushort_t* wf2, float* hOut)
{
    __shared__ ushort_t sA[16 * 520];
    __shared__ ushort_t sB[16 * 520];
    __shared__ float red[8][4][64][4];
    int g = blockIdx.x & 7;
    int loc = blockIdx.x >> 3;
    if (loc < 16)
        run_layer<0, 4, 10, 328>(g, loc, threadIdx.x, x, flags, bias, h1r, h2r, wf1, hOut, sA, sB, red);
    else
        run_layer<1, 6, 16, 520>(g, loc - 16, threadIdx.x, x, flags, bias, h1r, h2r, wf2, hOut, sA, sB, red);
}

// ---------------- head MLP ----------------

__global__ void head_mlp(const float* hOut, const float* W1, const float* b1,
                         const float* W2, const float* b2, const float* W3, const float* b3,
                         float* out)
{
    __shared__ float h[256];
    __shared__ float a1[128];
    __shared__ float a2[64];
    int b = blockIdx.x, j = threadIdx.x;
    for (int k = j; k < 256; k += 128)
        h[k] = ld_cg_f32(hOut + (size_t)b * HID + k);
    __syncthreads();
    float s = b1[j];
    for (int k = 0; k < 256; k++) s += W1[j * 256 + k] * h[k];
    a1[j] = fmaxf(s, 0.f);
    __syncthreads();
    if (j < 64) {
        float s2 = b2[j];
        for (int k = 0; k < 128; k++) s2 += W2[j * 128 + k] * a1[k];
        a2[j] = fmaxf(s2, 0.f);
    }
    __syncthreads();
    if (j == 0) {
        float s3 = b3[0];
        for (int k = 0; k < 64; k++) s3 += W3[k] * a2[k];
        out[b] = s3;
    }
}

// ---------------- launch ----------------

extern "C" void kernel_launch(void* const* d_in, const int* in_sizes, int n_in,
                              void* d_out, int out_size, void* d_ws, size_t ws_size,
                              hipStream_t stream)
{
    const float* x    = (const float*)d_in[0];
    const float* Wxh1 = (const float*)d_in[1];
    const float* bxh1 = (const float*)d_in[2];
    const float* Whh1 = (const float*)d_in[3];
    const float* bhh1 = (const float*)d_in[4];
    const float* Wxh2 = (const float*)d_in[5];
    const float* bxh2 = (const float*)d_in[6];
    const float* Whh2 = (const float*)d_in[7];
    const float* bhh2 = (const float*)d_in[8];
    const float* W1   = (const float*)d_in[9];
    const float* b1   = (const float*)d_in[10];
    const float* W2   = (const float*)d_in[11];
    const float* b2   = (const float*)d_in[12];
    const float* W3   = (const float*)d_in[13];
    const float* b3   = (const float*)d_in[14];

    char* w = (char*)d_ws;
    int*      flags = (int*)(w + OFF_FLAGS);
    float*    bias  = (float*)(w + OFF_BIAS);
    ushort_t* h1r   = (ushort_t*)(w + OFF_H1R);
    ushort_t* h2r   = (ushort_t*)(w + OFF_H2R);
    ushort_t* wf1   = (ushort_t*)(w + OFF_WF1);
    ushort_t* wf2   = (ushort_t*)(w + OFF_WF2);
    float*    hOut  = (float*)(w + OFF_HOUT);

    prep_misc<<<(2304 + 131072 + 255) / 256, 256, 0, stream>>>(bxh1, bhh1, bxh2, bhh2,
                                                               bias, flags, h1r, h2r);
    prep_wf<<<((WF1_FRAGS + WF2_FRAGS) * 512 + 255) / 256, 256, 0, stream>>>(
        Wxh1, Whh1, Wxh2, Whh2, wf1, wf2);

    const float* xp = x;
    void* args[] = { (void*)&xp, (void*)&flags, (void*)&bias,
                     (void*)&h1r, (void*)&h2r, (void*)&wf1, (void*)&wf2, (void*)&hOut };
    hipLaunchCooperativeKernel((void*)recur, dim3(256), dim3(512), args, 0, stream);

    head_mlp<<<NBATCH, 128, 0, stream>>>(hOut, W1, b1, W2, b2, W3, b3, (float*)d_out);
}